// Round 3
// baseline (125.215 us; speedup 1.0000x reference)
//
#include <hip/hip_runtime.h>
#include <math.h>

// B=2, HD=4, H=W=128, KSIZE=7 (K=49), NSP=9, S=64
#define BN   2
#define HDN  4
#define HN   128
#define WN   128
#define KS   7
#define KK   49
#define NSPN 9
#define SN   64
#define TPB  128     // 2 waves; each wave owns 16 pixels x 4 heads, fully autonomous
#define CH   788     // albuf chunk stride (dwords): 784 data + 4 pad (bank spread)
#define PIXSTR 60    // gather buf pixel stride (dwords): 16B-aligned, ~2-way banks

// v5: line-touch minimization. Model (validated v3/v4): time ~ distinct
// cache-line touches per CU x ~3cyc (TA/L1 tag throughput, per-CU shared ->
// occupancy-insensitive, matching v4's null result). attn/out were 196B-
// strided per lane: 64 lines touched per inst (13+13 insts = 1664/wave).
// Fix: stage both through wave-private LDS with FLAT coalesced global access
// (196 touches each). Gather: 4 patches/inst (14 lanes each: 7 rows x 2
// overlapping dwordx4) into [pix][7][8] LDS tiles - aligned b128 everywhere.
// pi comes free from inside the gathered patch (row hh-hs, col w-ws).
// Zero __syncthreads: all LDS regions wave-private, DS ops in-order per wave.
__global__ __launch_bounds__(TPB, 2) void attn_rw5(
    const float* __restrict__ attn,
    const float* __restrict__ sims,
    const int*   __restrict__ sinds,
    float*       __restrict__ out)
{
    __shared__ __align__(16) float albuf[2][4 * CH];      // per-wave 12.6 KB (attn in -> gather -> out)
    __shared__ __align__(16) int   gbuf[2][16 * NSPN];    // per-wave sinds (144 ints)

    const int t    = threadIdx.x;
    const int lane = t & 63;
    const int wv   = t >> 6;
    const int bx   = blockIdx.x;
    const int wseg = bx & 3;
    const int hh   = (bx >> 2) & 127;
    const int b    = bx >> 9;
    const int ww0  = wseg * 32 + wv * 16;   // wave's first absolute column

    const int pixL = lane >> 2;             // 0..15 (compute mapping)
    const int hd   = lane & 3;

    const float* simsB = sims + ((size_t)b << 20);
    int hs = hh - 3; hs = max(0, min(HN - KS, hs));
    const int dr = hh - hs;                 // 0..6, block-uniform

    float* al = albuf[wv];
    int*   gl = gbuf[wv];

    // ---------- stage attn (flat, coalesced) + sinds: ALL loads first ----------
    float4 areg[4][4];
    #pragma unroll
    for (int c = 0; c < 4; ++c) {
        const float* gsrc = attn + ((((size_t)b * HDN + c) * HN + hh) * WN + ww0) * (size_t)KK;
        #pragma unroll
        for (int j = 0; j < 4; ++j)
            if (j < 3 || lane < 4)                       // 784 dwords per chunk
                __builtin_memcpy(&areg[c][j], gsrc + j * 256 + lane * 4, 16);
    }
    int4 sreg = make_int4(0, 0, 0, 0);
    const int* ssrc = sinds + ((b * HN + hh) * WN + ww0) * NSPN;
    if (lane < 36)
        __builtin_memcpy(&sreg, ssrc + lane * 4, 16);    // 144 ints, coalesced

    if (lane < 36) *(int4*)(gl + lane * 4) = sreg;       // publish sinds (wave-private)

    // ---------- gather lane constants ----------
    int grp = lane / 14; grp = min(grp, 3);              // patch within inst
    const int  cp    = lane - grp * 14;                  // (lane%14 for active lanes)
    const int  grow  = cp >> 1;                          // 0..6
    const int  ghalf = cp & 1;                           // 0: cols 0-3, 1: cols 3-6
    const bool gact  = lane < 56;
    int pix_i[4], ws_i[4];
    #pragma unroll
    for (int i = 0; i < 4; ++i) {
        pix_i[i] = 4 * i + grp;
        int wabs = ww0 + pix_i[i];
        ws_i[i]  = max(0, min(WN - KS, wabs - 3));
    }
    const int rowoff = (hs + grow) * WN + ghalf * 3;     // per-lane row/half offset

    float4 gst[4];
    auto gather_issue = [&](int sp) {
        #pragma unroll
        for (int i = 0; i < 4; ++i) {
            int g = gl[pix_i[i] * NSPN + sp];            // ds_read_b32, per-lane
            const float* src = simsB + ((size_t)g << 14) + rowoff + ws_i[i];
            if (gact) __builtin_memcpy(&gst[i], src, 16);
        }
    };
    auto gather_write = [&](int buf) {
        float* pb0 = al + buf * 16 * PIXSTR;
        if (gact) {
            #pragma unroll
            for (int i = 0; i < 4; ++i)
                *(float4*)(pb0 + pix_i[i] * PIXSTR + grow * 8 + ghalf * 4) = gst[i];
        }
    };

    gather_issue(0);                                     // sp0 loads in flight early

    // ---------- publish attn to LDS, then redistribute to a[49] ----------
    #pragma unroll
    for (int c = 0; c < 4; ++c)
        #pragma unroll
        for (int j = 0; j < 4; ++j)
            if (j < 3 || lane < 4)
                *(float4*)(al + c * CH + j * 256 + lane * 4) = areg[c][j];

    const int abase = hd * CH + pixL * KK;               // ~2-way banks (free)
    float a[KK];
    #pragma unroll
    for (int k = 0; k < KK; ++k) a[k] = al[abase + k];   // ds_read2_b32 pairs

    // softmax (pure VALU - covers gather(0) flight)
    {
        float m0 = a[0], m1 = a[1], m2 = a[2], m3 = a[3];
        #pragma unroll
        for (int k = 4; k < KK; k += 4) {
            m0 = fmaxf(m0, a[k]);
            if (k + 1 < KK) m1 = fmaxf(m1, a[k + 1]);
            if (k + 2 < KK) m2 = fmaxf(m2, a[k + 2]);
            if (k + 3 < KK) m3 = fmaxf(m3, a[k + 3]);
        }
        float m = fmaxf(fmaxf(m0, m1), fmaxf(m2, m3));
        #pragma unroll
        for (int k = 0; k < KK; ++k) a[k] = __expf(a[k] - m);
    }

    gather_write(0);                                     // after a[] reads (in-order DS)

    // pi location inside own patch: row dr, col dc (slot bump past dup col 3)
    const int wabs_s = ww0 + pixL;
    const int ws_s   = max(0, min(WN - KS, wabs_s - 3));
    const int dc     = wabs_s - ws_s;                    // 0..6
    const int dcs    = dc + (dc > 3 ? 1 : 0);
    const int pioff  = pixL * PIXSTR + dr * 8 + dcs;

    float acc[KK];
    #pragma unroll
    for (int k = 0; k < KK; ++k) acc[k] = 0.0f;

    #define P(k) p[(k) / KS][(k) % KS]

    for (int sp = 0; sp < NSPN; ++sp) {
        const int buf = sp & 1;
        if (sp + 1 < NSPN) gather_issue(sp + 1);         // next plane in flight

        const float* prow = al + buf * 16 * PIXSTR + pixL * PIXSTR;
        float p[KS][KS];
        #pragma unroll
        for (int r = 0; r < KS; ++r) {
            float4 lo = *(const float4*)(prow + r * 8);      // cols 0-3
            float4 hi = *(const float4*)(prow + r * 8 + 4);  // cols 3-6
            p[r][0] = lo.x; p[r][1] = lo.y; p[r][2] = lo.z; p[r][3] = lo.w;
            p[r][4] = hi.y; p[r][5] = hi.z; p[r][6] = hi.w;
        }
        float pi = al[buf * 16 * PIXSTR + pioff];

        // denom: 4-way split FMA chains over k = r*7+c
        float d0 = 0.f, d1 = 0.f, d2 = 0.f, d3 = 0.f;
        #pragma unroll
        for (int k = 0; k < 48; k += 4) {
            d0 = fmaf(a[k + 0], P(k + 0), d0);
            d1 = fmaf(a[k + 1], P(k + 1), d1);
            d2 = fmaf(a[k + 2], P(k + 2), d2);
            d3 = fmaf(a[k + 3], P(k + 3), d3);
        }
        d0 = fmaf(a[48], P(48), d0);
        float d    = (d0 + d1) + (d2 + d3);
        float coef = pi * __builtin_amdgcn_rcpf(d + 1e-10f);

        #pragma unroll
        for (int k = 0; k < KK; ++k) acc[k] = fmaf(coef, P(k), acc[k]);

        if (sp + 1 < NSPN) gather_write(buf ^ 1);        // in-order DS; no barrier
    }
    #undef P

    // ---------- out: regs -> LDS (same layout as attn) -> flat coalesced stores ----------
    #pragma unroll
    for (int k = 0; k < KK; ++k) al[abase + k] = a[k] * acc[k];   // ds_write2_b32 pairs

    #pragma unroll
    for (int c = 0; c < 4; ++c) {
        float* gdst = out + ((((size_t)b * HDN + c) * HN + hh) * WN + ww0) * (size_t)KK;
        #pragma unroll
        for (int j = 0; j < 4; ++j)
            if (j < 3 || lane < 4) {
                float4 v = *(const float4*)(al + c * CH + j * 256 + lane * 4);
                __builtin_memcpy(gdst + j * 256 + lane * 4, &v, 16);
            }
    }
}

extern "C" void kernel_launch(void* const* d_in, const int* in_sizes, int n_in,
                              void* d_out, int out_size, void* d_ws, size_t ws_size,
                              hipStream_t stream) {
    const float* attn  = (const float*)d_in[0];
    const float* sims  = (const float*)d_in[1];
    const int*   sinds = (const int*)d_in[2];
    float*       outp  = (float*)d_out;

    // blocks: b(2) x hh(128) x wseg(4) = 1024, 2 autonomous waves each
    const int blocks = BN * HN * (WN / 32);
    attn_rw5<<<blocks, TPB, 0, stream>>>(attn, sims, sinds, outp);
}